// Round 4
// baseline (268.963 us; speedup 1.0000x reference)
//
#include <hip/hip_runtime.h>
#include <hip/hip_bf16.h>

// AAConv2d: B=8, CIN=128, H=W=32, COUT=128, K=3, DK=DV=64, NH=8, dkh=dvh=8
// out[:, 0:64]  = conv3x3(x, w_general) + b_general
// out[:, 64:128]= conv3x3(attn_combined, w_out) + b_out
// Attention faithful to the reference's raw reshape: flat_q row n = the 8
// contiguous floats at offset n*8 of the (d,y,x)-flattened q slice.
// Rel logits (re-derived; BOTH terms read q at row=m>>5, col=n>>5):
//   logits[n,m] += dot(q[:, m>>5, n>>5], krw[(m&31)-(m>>5)+31])
//               +  dot(q[:, m>>5, n>>5], krh[(n&31)-(n>>5)+31])
// Input/output dtype (bf16 vs fp32) detected at runtime; compute is fp32 on
// canonicalized workspace copies.

#define NP 1024
#define QSCALE 2.8284271247461903f   // q / (8^-0.5) = q*sqrt(8)

using bf16 = __hip_bfloat16;

__device__ __forceinline__ float b2f(bf16 v) { return __bfloat162float(v); }

__device__ __forceinline__ float dot8(const float* a, const float* b) {
  float s = a[0] * b[0];
  s = fmaf(a[1], b[1], s); s = fmaf(a[2], b[2], s); s = fmaf(a[3], b[3], s);
  s = fmaf(a[4], b[4], s); s = fmaf(a[5], b[5], s); s = fmaf(a[6], b[6], s);
  s = fmaf(a[7], b[7], s);
  return s;
}

// ---------------------------------------------------------------------------
// Kernel 0: dtype detector. Test bits 14:7 of each fp32 word = the LOW bf16
// element's exponent field. bf16 N(0,1) data: in [64,133] essentially always
// (|v| in [2^-63, 2^7)). fp32 data: those bits are uniform mantissa bits ->
// pass prob ~70/256=0.27. cnt over 1024 words: bf16 ~1024, fp32 ~280.
// ---------------------------------------------------------------------------
__global__ __launch_bounds__(256) void detect_kernel(
    const unsigned* __restrict__ xraw, int* __restrict__ flag)
{
  __shared__ int partial[4];
  int t = threadIdx.x;
  int cnt = 0;
  for (int i = t; i < 1024; i += 256) {
    unsigned elo = (xraw[i] >> 7) & 0xffu;
    cnt += (elo >= 64u && elo <= 133u) ? 1 : 0;
  }
#pragma unroll
  for (int off = 1; off < 64; off <<= 1) cnt += __shfl_xor(cnt, off);
  if ((t & 63) == 0) partial[t >> 6] = cnt;
  __syncthreads();
  if (t == 0) {
    int tot = partial[0] + partial[1] + partial[2] + partial[3];
    *flag = (tot >= 650) ? 0 : 1;   // 1 = fp32 tensors, 0 = bf16 tensors
  }
}

// ---------------------------------------------------------------------------
// Kernel 0b: canonicalize all 9 inputs to fp32 in workspace.
// ---------------------------------------------------------------------------
__global__ __launch_bounds__(256) void cvt_kernel(
    const void* __restrict__ p0, const void* __restrict__ p1, const void* __restrict__ p2,
    const void* __restrict__ p3, const void* __restrict__ p4, const void* __restrict__ p5,
    const void* __restrict__ p6, const void* __restrict__ p7, const void* __restrict__ p8,
    float* __restrict__ ws, const int* __restrict__ flag)
{
  const void* src[9] = {p0, p1, p2, p3, p4, p5, p6, p7, p8};
  const int   n[9]    = {1048576, 73728, 64, 24576, 192, 36864, 64, 504, 504};
  const int   doff[9] = {0, 1048576, 1183744, 1122304, 1183808, 1146880, 1184000, 1184064, 1184568};
  int f32 = *flag;
  int gsz = gridDim.x * 256;
  int gid = blockIdx.x * 256 + threadIdx.x;
#pragma unroll
  for (int s = 0; s < 9; s++) {
    float* dst = ws + doff[s];
    int ns = n[s];
    if (f32) {
      const float* sp = (const float*)src[s];
      for (int i = gid; i < ns; i += gsz) dst[i] = sp[i];
    } else {
      const bf16* sp = (const bf16*)src[s];
      for (int i = gid; i < ns; i += gsz) dst[i] = b2f(sp[i]);
    }
  }
}

// ---------------------------------------------------------------------------
// Kernel 1: qkv 1x1 conv (fp32). grid (b=8, pg=16, cog=6), 256 threads.
// Block: 32 co x 64 px. co [0,64)->qbuf (scaled), [64,128)->kbuf, [128,192)->vbuf.
// ---------------------------------------------------------------------------
__global__ __launch_bounds__(256) void qkv_kernel(
    const float* __restrict__ xf, const float* __restrict__ wf, const float* __restrict__ bias,
    float* __restrict__ qbuf, float* __restrict__ kbuf, float* __restrict__ vbuf)
{
  __shared__ float xt[128][64];   // 32 KB
  __shared__ float wt[32][128];   // 16 KB
  int b = blockIdx.x, pg = blockIdx.y, cog = blockIdx.z;
  int t = threadIdx.x;
  int p0 = pg * 64;
  const float* xs = xf + (size_t)b * 131072;
  for (int idx = t; idx < 8192; idx += 256) {
    int ci = idx >> 6, p = idx & 63;
    xt[ci][p] = xs[ci * 1024 + p0 + p];
  }
  for (int idx = t; idx < 4096; idx += 256) {
    int co = idx >> 7, ci = idx & 127;
    wt[co][ci] = wf[(cog * 32 + co) * 128 + ci];
  }
  __syncthreads();

  int cog2 = t >> 6, pl = t & 63;
  float acc[8] = {0.f, 0.f, 0.f, 0.f, 0.f, 0.f, 0.f, 0.f};
  for (int ci = 0; ci < 128; ci++) {
    float xv = xt[ci][pl];
#pragma unroll
    for (int j = 0; j < 8; j++) acc[j] = fmaf(xv, wt[cog2 * 8 + j][ci], acc[j]);
  }
#pragma unroll
  for (int j = 0; j < 8; j++) {
    int co = cog * 32 + cog2 * 8 + j;
    float v = acc[j] + bias[co];
    float* dst;
    if (co < 64) { dst = qbuf; v *= QSCALE; }
    else if (co < 128) dst = kbuf;
    else dst = vbuf;
    dst[((size_t)b * 64 + (co & 63)) * NP + p0 + pl] = v;
  }
}

// ---------------------------------------------------------------------------
// Kernel 2: attention. grid (cp=16, h=8, b=8), 256 threads.
// Block handles rows n in [cp*64, cp*64+64), i.e. q-COLUMN blocks C0, C0+1.
// Thread: 8 rows x 32 m-segments. Exact two-pass softmax; K/V stream from
// global (L2-resident). Tables:
//   qsT[cs][r][d]   = q[d][row=r][col=C0+cs]
//   bw2[cs][m]      = dot(q[:, m>>5, C], krw[(m&31)-(m>>5)+31])
//   bhT[cs][i][J]   = dot(q[:, i,    C], krh[J-C+31])       (i = m>>5, J = n&31)
// ---------------------------------------------------------------------------
__global__ __launch_bounds__(256) void attn_kernel(
    const float* __restrict__ qbuf, const float* __restrict__ kbuf, const float* __restrict__ vbuf,
    const float* __restrict__ krh, const float* __restrict__ krw,
    float* __restrict__ abuf)
{
  __shared__ float bw2[2][NP];
  __shared__ float bhT[2][32][32];
  __shared__ float qsT[2][32][8];
  __shared__ float krhs[64][8];        // 63 rows used
  __shared__ float krws[64][8];

  int t = threadIdx.x;
  int cp = blockIdx.x, h = blockIdx.y, b = blockIdx.z;
  int C0 = cp * 2;
  const float* qbase = qbuf + ((size_t)b * 64 + h * 8) * NP;
  const float* kbase = kbuf + ((size_t)b * 64 + h * 8) * NP;
  const float* vbase = vbuf + ((size_t)b * 64 + h * 8) * NP;

  for (int idx = t; idx < 63 * 8; idx += 256) {
    krhs[idx >> 3][idx & 7] = krh[idx];
    krws[idx >> 3][idx & 7] = krw[idx];
  }
  for (int idx = t; idx < 512; idx += 256) {
    int cs = idx >> 8, d = (idx >> 5) & 7, r = idx & 31;
    qsT[cs][r][d] = qbase[(size_t)d * NP + r * 32 + (C0 + cs)];   // q[d][row=r][col=C]
  }
  __syncthreads();

  for (int idx = t; idx < 2048; idx += 256) {
    int cs = idx >> 10, m = idx & 1023;
    int rg = m >> 5, j2 = m & 31;
    bw2[cs][m] = dot8(qsT[cs][rg], krws[j2 - rg + 31]);
  }
  for (int idx = t; idx < 2048; idx += 256) {
    int cs = idx >> 10, r = idx & 1023;
    int i = r >> 5, J = r & 31;
    bhT[cs][i][J] = dot8(qsT[cs][i], krhs[J - (C0 + cs) + 31]);
  }
  __syncthreads();

  int Csub = t >> 7, rowg = (t >> 5) & 3, seg = t & 31;
  int C = C0 + Csub;

  const float* qrow = qbase + (size_t)C * 256 + rowg * 64;   // flat_q rows n = C*32 + rowg*8 + r
  float q[8][8];
#pragma unroll
  for (int r = 0; r < 8; r++)
#pragma unroll
    for (int d = 0; d < 8; d++) q[r][d] = qrow[r * 8 + d];

  const float* bwX = bw2[Csub];

  // ---- pass 1: exact row max ----
  float M[8];
#pragma unroll
  for (int r = 0; r < 8; r++) M[r] = -3.0e38f;

  for (int i = 0; i < 32; ++i) {
    int m = i * 32 + seg;
    const float2* kp = (const float2*)(kbase + (size_t)m * 8);
    float2 k01 = kp[0], k23 = kp[1], k45 = kp[2], k67 = kp[3];
    float kk[8] = {k01.x, k01.y, k23.x, k23.y, k45.x, k45.y, k67.x, k67.y};
    float bwv = bwX[m];
    const float2* bhp = (const float2*)&bhT[Csub][i][rowg * 8];
    float2 bhA = bhp[0], bhB = bhp[1], bhC = bhp[2], bhD = bhp[3];
    float bhv[8] = {bhA.x, bhA.y, bhB.x, bhB.y, bhC.x, bhC.y, bhD.x, bhD.y};
#pragma unroll
    for (int r = 0; r < 8; ++r) {
      float dt = dot8(q[r], kk);
      M[r] = fmaxf(M[r], dt + bwv + bhv[r]);
    }
  }
#pragma unroll
  for (int off = 1; off < 32; off <<= 1)
#pragma unroll
    for (int r = 0; r < 8; r++) M[r] = fmaxf(M[r], __shfl_xor(M[r], off));

  // ---- pass 2: exp accumulate ----
  float l[8], O[8][8];
#pragma unroll
  for (int r = 0; r < 8; r++) {
    l[r] = 0.f;
#pragma unroll
    for (int d = 0; d < 8; d++) O[r][d] = 0.f;
  }

  for (int i = 0; i < 32; ++i) {
    int m = i * 32 + seg;
    const float2* kp = (const float2*)(kbase + (size_t)m * 8);
    float2 k01 = kp[0], k23 = kp[1], k45 = kp[2], k67 = kp[3];
    float kk[8] = {k01.x, k01.y, k23.x, k23.y, k45.x, k45.y, k67.x, k67.y};
    const float2* vp = (const float2*)(vbase + (size_t)m * 8);
    float2 v01 = vp[0], v23 = vp[1], v45 = vp[2], v67 = vp[3];
    float vv[8] = {v01.x, v01.y, v23.x, v23.y, v45.x, v45.y, v67.x, v67.y};
    float bwv = bwX[m];
    const float2* bhp = (const float2*)&bhT[Csub][i][rowg * 8];
    float2 bhA = bhp[0], bhB = bhp[1], bhC = bhp[2], bhD = bhp[3];
    float bhv[8] = {bhA.x, bhA.y, bhB.x, bhB.y, bhC.x, bhC.y, bhD.x, bhD.y};
#pragma unroll
    for (int r = 0; r < 8; ++r) {
      float dt = dot8(q[r], kk);
      float p = __expf(fminf(dt + bwv + bhv[r] - M[r], 0.f));
      l[r] += p;
#pragma unroll
      for (int d = 0; d < 8; ++d) O[r][d] = fmaf(p, vv[d], O[r][d]);
    }
  }

#pragma unroll
  for (int off = 1; off < 32; off <<= 1) {
#pragma unroll
    for (int r = 0; r < 8; r++) {
      l[r] += __shfl_xor(l[r], off);
#pragma unroll
      for (int d = 0; d < 8; d++) O[r][d] += __shfl_xor(O[r][d], off);
    }
  }
  if (seg == 0) {
#pragma unroll
    for (int r = 0; r < 8; r++) {
      float inv = 1.f / l[r];   // l >= 1 by exact max: no inf possible
      int n = C * 32 + rowg * 8 + r;
#pragma unroll
      for (int d = 0; d < 8; d++)
        abuf[((size_t)b * 64 + h * 8 + d) * NP + n] = O[r][d] * inv;
    }
  }
}

// ---------------------------------------------------------------------------
// Kernel 3: direct 3x3 conv, pad 1, stride 1, Cout=64, H=W=32 (fp32 in/weights).
// grid (rg=4, coG=8, b=8), 256 threads. Tile: 8 co x 8 rows x 32 cols.
// Output store dual-dtype per flag.
// ---------------------------------------------------------------------------
template <int CINT>
__global__ __launch_bounds__(256) void conv3x3_kernel(
    const float* __restrict__ in,    // [8][CINT][32][32]
    const float* __restrict__ wgt,   // [64][CINT][3][3]
    const float* __restrict__ bias,  // [64]
    void* __restrict__ out,          // [8][128][32][32] bf16 or fp32
    int co_base, const int* __restrict__ flag)
{
  __shared__ float xt[16][10][34];
  __shared__ float wt[8][16][12];
  int rg = blockIdx.x, coG = blockIdx.y, b = blockIdx.z;
  int y0 = rg * 8;
  int t = threadIdx.x;
  int cog2 = t >> 7;
  int pg = t & 127;
  int row = pg >> 4, col = (pg & 15) * 2;

  float acc[4][2] = {{0.f, 0.f}, {0.f, 0.f}, {0.f, 0.f}, {0.f, 0.f}};

  for (int ci0 = 0; ci0 < CINT; ci0 += 16) {
    __syncthreads();
    {
      int pair = t >> 1, half = t & 1;
      for (int s = pair; s < 160; s += 128) {
        int ci = s / 10, rr = s - ci * 10;
        int gy = y0 - 1 + rr;
        const float* src = in + ((size_t)b * CINT + ci0 + ci) * 1024;
        int cc0 = half * 17;
        for (int cc = cc0; cc < cc0 + 17; cc++) {
          int gx = cc - 1;
          float v = 0.f;
          if ((unsigned)gy < 32u && (unsigned)gx < 32u) v = src[gy * 32 + gx];
          xt[ci][rr][cc] = v;
        }
      }
    }
    for (int s = t; s < 128; s += 256) {
      int co = s >> 4, ci = s & 15;
      const float* ws = wgt + ((size_t)(coG * 8 + co) * CINT + ci0 + ci) * 9;
#pragma unroll
      for (int k = 0; k < 9; k++) wt[co][ci][k] = ws[k];
    }
    __syncthreads();

    for (int ci = 0; ci < 16; ci++) {
      float xr[3][4];
#pragma unroll
      for (int ky = 0; ky < 3; ky++) {
        const float2* xp = (const float2*)&xt[ci][row + ky][col];
        float2 a = xp[0], c = xp[1];
        xr[ky][0] = a.x; xr[ky][1] = a.y; xr[ky][2] = c.x; xr[ky][3] = c.y;
      }
#pragma unroll
      for (int j = 0; j < 4; j++) {
        const float* wp = wt[cog2 * 4 + j][ci];
#pragma unroll
        for (int ky = 0; ky < 3; ky++)
#pragma unroll
          for (int kx = 0; kx < 3; kx++) {
            float wv = wp[ky * 3 + kx];
            acc[j][0] = fmaf(xr[ky][kx], wv, acc[j][0]);
            acc[j][1] = fmaf(xr[ky][kx + 1], wv, acc[j][1]);
          }
      }
    }
  }

  int f32 = *flag;
  int yy = y0 + row;
#pragma unroll
  for (int j = 0; j < 4; j++) {
    int co = coG * 8 + cog2 * 4 + j;
    float bv = bias[co];
    float v0 = acc[j][0] + bv, v1 = acc[j][1] + bv;
    size_t eoff = ((size_t)b * 128 + co_base + co) * 1024 + yy * 32 + col;
    if (f32) {
      float* op = (float*)out + eoff;
      op[0] = v0; op[1] = v1;
    } else {
      bf16* op = (bf16*)out + eoff;
      op[0] = __float2bfloat16(v0);
      op[1] = __float2bfloat16(v1);
    }
  }
}

// ---------------------------------------------------------------------------
extern "C" void kernel_launch(void* const* d_in, const int* in_sizes, int n_in,
                              void* d_out, int out_size, void* d_ws, size_t ws_size,
                              hipStream_t stream) {
  float* ws    = (float*)d_ws;
  float* xf    = ws;                 // 1048576
  float* wgf   = ws + 1048576;       // 73728
  float* wqkvf = ws + 1122304;       // 24576
  float* wof   = ws + 1146880;       // 36864
  float* bgf   = ws + 1183744;       // 64
  float* bqkvf = ws + 1183808;       // 192
  float* bof   = ws + 1184000;       // 64
  float* krhf  = ws + 1184064;       // 504
  float* krwf  = ws + 1184568;       // 504
  float* qbuf  = ws + 1185280;       // 524288
  float* kbuf  = qbuf + 524288;
  float* vbuf  = kbuf + 524288;
  float* abuf  = vbuf + 524288;
  int*   flag  = (int*)(ws + 3282432);

  detect_kernel<<<1, 256, 0, stream>>>((const unsigned*)d_in[0], flag);
  cvt_kernel<<<512, 256, 0, stream>>>(d_in[0], d_in[1], d_in[2], d_in[3], d_in[4],
                                      d_in[5], d_in[6], d_in[7], d_in[8], ws, flag);
  qkv_kernel<<<dim3(8, 16, 6), 256, 0, stream>>>(xf, wqkvf, bqkvf, qbuf, kbuf, vbuf);
  conv3x3_kernel<128><<<dim3(4, 8, 8), 256, 0, stream>>>(xf, wgf, bgf, d_out, 0, flag);
  attn_kernel<<<dim3(16, 8, 8), 256, 0, stream>>>(qbuf, kbuf, vbuf, krhf, krwf, abuf);
  conv3x3_kernel<64><<<dim3(4, 8, 8), 256, 0, stream>>>(abuf, wof, bof, d_out, 64, flag);
}

// Round 5
// 248.772 us; speedup vs baseline: 1.0812x; 1.0812x over previous
//
#include <hip/hip_runtime.h>
#include <hip/hip_bf16.h>

// AAConv2d: B=8, CIN=128, H=W=32, COUT=128, K=3, DK=DV=64, NH=8, dkh=dvh=8
// out[:, 0:64]  = conv3x3(x, w_general) + b_general
// out[:, 64:128]= conv3x3(attn_combined, w_out) + b_out
// Rel logits (verified round 4): logits[n,m] += dot(q[:, m>>5, n>>5], krw[(m&31)-(m>>5)+31])
//                                            + dot(q[:, m>>5, n>>5], krh[(n&31)-(n>>5)+31])
// dtype detected at runtime (confirmed fp32 in practice); compute fp32.

#define NP 1024
#define QSCALE 2.8284271247461903f   // q / (8^-0.5) = q*sqrt(8)
#define LOG2E  1.4426950408889634f

using bf16 = __hip_bfloat16;

__device__ __forceinline__ float b2f(bf16 v) { return __bfloat162float(v); }

__device__ __forceinline__ float dot8(const float* a, const float* b) {
  float s = a[0] * b[0];
  s = fmaf(a[1], b[1], s); s = fmaf(a[2], b[2], s); s = fmaf(a[3], b[3], s);
  s = fmaf(a[4], b[4], s); s = fmaf(a[5], b[5], s); s = fmaf(a[6], b[6], s);
  s = fmaf(a[7], b[7], s);
  return s;
}

__device__ __forceinline__ int fenc(float f) { int i = __float_as_int(f); return i < 0 ? (i ^ 0x7fffffff) : i; }
__device__ __forceinline__ float fdec(int i) { return __int_as_float(i < 0 ? (i ^ 0x7fffffff) : i); }

#if defined(__has_builtin)
#if __has_builtin(__builtin_amdgcn_exp2f)
#define EXP2F __builtin_amdgcn_exp2f
#else
#define EXP2F exp2f
#endif
#else
#define EXP2F exp2f
#endif

// ---------------------------------------------------------------------------
// Kernel 0: dtype detector (bits 14:7 = low-bf16 exponent test).
// ---------------------------------------------------------------------------
__global__ __launch_bounds__(256) void detect_kernel(
    const unsigned* __restrict__ xraw, int* __restrict__ flag)
{
  __shared__ int partial[4];
  int t = threadIdx.x;
  int cnt = 0;
  for (int i = t; i < 1024; i += 256) {
    unsigned elo = (xraw[i] >> 7) & 0xffu;
    cnt += (elo >= 64u && elo <= 133u) ? 1 : 0;
  }
#pragma unroll
  for (int off = 1; off < 64; off <<= 1) cnt += __shfl_xor(cnt, off);
  if ((t & 63) == 0) partial[t >> 6] = cnt;
  __syncthreads();
  if (t == 0) {
    int tot = partial[0] + partial[1] + partial[2] + partial[3];
    *flag = (tot >= 650) ? 0 : 1;   // 1 = fp32 tensors, 0 = bf16 tensors
  }
}

// ---------------------------------------------------------------------------
// Kernel 0b: canonicalize all 9 inputs to fp32 in workspace.
// ---------------------------------------------------------------------------
__global__ __launch_bounds__(256) void cvt_kernel(
    const void* __restrict__ p0, const void* __restrict__ p1, const void* __restrict__ p2,
    const void* __restrict__ p3, const void* __restrict__ p4, const void* __restrict__ p5,
    const void* __restrict__ p6, const void* __restrict__ p7, const void* __restrict__ p8,
    float* __restrict__ ws, const int* __restrict__ flag)
{
  const void* src[9] = {p0, p1, p2, p3, p4, p5, p6, p7, p8};
  const int   n[9]    = {1048576, 73728, 64, 24576, 192, 36864, 64, 504, 504};
  const int   doff[9] = {0, 1048576, 1183744, 1122304, 1183808, 1146880, 1184000, 1184064, 1184568};
  int f32 = *flag;
  int gsz = gridDim.x * 256;
  int gid = blockIdx.x * 256 + threadIdx.x;
#pragma unroll
  for (int s = 0; s < 9; s++) {
    float* dst = ws + doff[s];
    int ns = n[s];
    if (f32) {
      const float* sp = (const float*)src[s];
      for (int i = gid; i < ns; i += gsz) dst[i] = sp[i];
    } else {
      const bf16* sp = (const bf16*)src[s];
      for (int i = gid; i < ns; i += gsz) dst[i] = b2f(sp[i]);
    }
  }
}

// ---------------------------------------------------------------------------
// Kernel 1: qkv 1x1 conv (fp32). grid (b=8, pg=16, cog=6), 256 threads.
// ---------------------------------------------------------------------------
__global__ __launch_bounds__(256) void qkv_kernel(
    const float* __restrict__ xf, const float* __restrict__ wf, const float* __restrict__ bias,
    float* __restrict__ qbuf, float* __restrict__ kbuf, float* __restrict__ vbuf)
{
  __shared__ float xt[128][64];   // 32 KB
  __shared__ float wt[32][128];   // 16 KB
  int b = blockIdx.x, pg = blockIdx.y, cog = blockIdx.z;
  int t = threadIdx.x;
  int p0 = pg * 64;
  const float* xs = xf + (size_t)b * 131072;
  for (int idx = t; idx < 8192; idx += 256) {
    int ci = idx >> 6, p = idx & 63;
    xt[ci][p] = xs[ci * 1024 + p0 + p];
  }
  for (int idx = t; idx < 4096; idx += 256) {
    int co = idx >> 7, ci = idx & 127;
    wt[co][ci] = wf[(cog * 32 + co) * 128 + ci];
  }
  __syncthreads();

  int cog2 = t >> 6, pl = t & 63;
  float acc[8] = {0.f, 0.f, 0.f, 0.f, 0.f, 0.f, 0.f, 0.f};
  for (int ci = 0; ci < 128; ci++) {
    float xv = xt[ci][pl];
#pragma unroll
    for (int j = 0; j < 8; j++) acc[j] = fmaf(xv, wt[cog2 * 8 + j][ci], acc[j]);
  }
#pragma unroll
  for (int j = 0; j < 8; j++) {
    int co = cog * 32 + cog2 * 8 + j;
    float v = acc[j] + bias[co];
    float* dst;
    if (co < 64) { dst = qbuf; v *= QSCALE; }
    else if (co < 128) dst = kbuf;
    else dst = vbuf;
    dst[((size_t)b * 64 + (co & 63)) * NP + p0 + pl] = v;
  }
}

// ---------------------------------------------------------------------------
// Kernel 2: attention, single-pass upper-bound softmax.
// grid (cp=16, h=8, b=8), 256 threads, __launch_bounds__(256,2) (VGPR<=256).
// Thread: (Csub=t>>7, rowg=(t>>5)&3, seg=t&31) -> 8 rows x 32 m-segments.
// All bias tables and q pre-scaled by log2e; p = exp2(dot8 seeded with bias).
// M_r = ||q_r||*kmax + bwmax + bhmax (scaled) is a safe upper bound:
// slack <= ~45 << 126, so exp2 never underflows to total-zero l.
// K staged in LDS (stride-12 rows, b128-aligned); V streams from L1/L2.
// ---------------------------------------------------------------------------
__global__ __launch_bounds__(256, 2) void attn_kernel(
    const float* __restrict__ qbuf, const float* __restrict__ kbuf, const float* __restrict__ vbuf,
    const float* __restrict__ krh, const float* __restrict__ krw,
    float* __restrict__ abuf)
{
  __shared__ float Kt[NP][12];         // 48 KB, row m at [m][0..7]
  __shared__ float bw2[2][NP];         // 8 KB  (scaled by log2e)
  __shared__ float bhT[2][32][32];     // 8 KB  (scaled by log2e)
  __shared__ float qsT[2][32][8];      // 2 KB  (unscaled)
  __shared__ float krhs[64][8];        // 2 KB
  __shared__ float krws[64][8];        // 2 KB
  __shared__ int smax[3];              // bits(kmax^2), fenc(bwmax_s), fenc(bhmax_s)

  int t = threadIdx.x;
  int cp = blockIdx.x, h = blockIdx.y, b = blockIdx.z;
  int C0 = cp * 2;
  const float* qbase = qbuf + ((size_t)b * 64 + h * 8) * NP;
  const float* kbase = kbuf + ((size_t)b * 64 + h * 8) * NP;
  const float* vbase = vbuf + ((size_t)b * 64 + h * 8) * NP;

  if (t < 3) smax[t] = (t == 0) ? 0 : fenc(-3.0e38f);

  for (int idx = t; idx < 63 * 8; idx += 256) {
    krhs[idx >> 3][idx & 7] = krh[idx];
    krws[idx >> 3][idx & 7] = krw[idx];
  }
  for (int idx = t; idx < 512; idx += 256) {
    int cs = idx >> 8, d = (idx >> 5) & 7, r = idx & 31;
    qsT[cs][r][d] = qbase[(size_t)d * NP + r * 32 + (C0 + cs)];   // q[d][row=r][col=C]
  }
  // stage K rows, track max ||k||^2
  float kn2 = 0.f;
#pragma unroll
  for (int rr = 0; rr < 4; rr++) {
    int m = rr * 256 + t;
    const float4* ks = (const float4*)(kbase + (size_t)m * 8);
    float4 a = ks[0], c = ks[1];
    float4* kd = (float4*)&Kt[m][0];
    kd[0] = a; kd[1] = c;
    float nn = a.x * a.x + a.y * a.y + a.z * a.z + a.w * a.w +
               c.x * c.x + c.y * c.y + c.z * c.z + c.w * c.w;
    kn2 = fmaxf(kn2, nn);
  }
  __syncthreads();
  atomicMax(&smax[0], __float_as_int(kn2));   // kn2 >= 0: raw bits monotone

  // build scaled bias tables + maxes
  float bwm = -3.0e38f;
  for (int idx = t; idx < 2048; idx += 256) {
    int cs = idx >> 10, m = idx & 1023;
    int rg = m >> 5, j2 = m & 31;
    float s = dot8(qsT[cs][rg], krws[j2 - rg + 31]) * LOG2E;
    bw2[cs][m] = s;
    bwm = fmaxf(bwm, s);
  }
  float bhm = -3.0e38f;
  for (int idx = t; idx < 2048; idx += 256) {
    int cs = idx >> 10, r = idx & 1023;
    int i = r >> 5, J = r & 31;
    float s = dot8(qsT[cs][i], krhs[J - (C0 + cs) + 31]) * LOG2E;
    bhT[cs][i][J] = s;
    bhm = fmaxf(bhm, s);
  }
  atomicMax(&smax[1], fenc(bwm));
  atomicMax(&smax[2], fenc(bhm));
  __syncthreads();

  float kmaxn = sqrtf(__int_as_float(smax[0]));
  float bmax = fdec(smax[1]) + fdec(smax[2]);

  int Csub = t >> 7, rowg = (t >> 5) & 3, seg = t & 31;
  int C = C0 + Csub;

  // load 8 q rows (flat_q rows n = C*32 + rowg*8 + r), pre-scale by log2e
  const float* qrow = qbase + (size_t)C * 256 + rowg * 64;
  float q[8][8], M[8], l[8], O[8][8];
#pragma unroll
  for (int r = 0; r < 8; r++) {
    float nn = 0.f;
#pragma unroll
    for (int d = 0; d < 8; d++) {
      float v = qrow[r * 8 + d] * LOG2E;
      q[r][d] = v;
      nn = fmaf(v, v, nn);
    }
    M[r] = sqrtf(nn) * kmaxn + bmax;   // scaled-domain upper bound
    l[r] = 0.f;
#pragma unroll
    for (int d = 0; d < 8; d++) O[r][d] = 0.f;
  }

  const float* bwX = bw2[Csub];
  for (int i = 0; i < 32; ++i) {
    int m = i * 32 + seg;
    const float4* kp = (const float4*)&Kt[m][0];
    float4 ka = kp[0], kc = kp[1];
    float kk[8] = {ka.x, ka.y, ka.z, ka.w, kc.x, kc.y, kc.z, kc.w};
    const float4* vp = (const float4*)(vbase + (size_t)m * 8);
    float4 va = vp[0], vc = vp[1];
    float vv[8] = {va.x, va.y, va.z, va.w, vc.x, vc.y, vc.z, vc.w};
    float bwv = bwX[m];
    const float4* bhp = (const float4*)&bhT[Csub][i][rowg * 8];
    float4 bhA = bhp[0], bhB = bhp[1];
    float cr[8] = {bhA.x, bhA.y, bhA.z, bhA.w, bhB.x, bhB.y, bhB.z, bhB.w};
#pragma unroll
    for (int r = 0; r < 8; ++r) {
      float s = bwv + (cr[r] - M[r]);
      s = fmaf(q[r][0], kk[0], s); s = fmaf(q[r][1], kk[1], s);
      s = fmaf(q[r][2], kk[2], s); s = fmaf(q[r][3], kk[3], s);
      s = fmaf(q[r][4], kk[4], s); s = fmaf(q[r][5], kk[5], s);
      s = fmaf(q[r][6], kk[6], s); s = fmaf(q[r][7], kk[7], s);
      float p = EXP2F(s);
      l[r] += p;
#pragma unroll
      for (int d = 0; d < 8; ++d) O[r][d] = fmaf(p, vv[d], O[r][d]);
    }
  }

  // reduce over the 32 segment lanes (xor offsets < 32 stay in 32-lane halves)
#pragma unroll
  for (int off = 1; off < 32; off <<= 1) {
#pragma unroll
    for (int r = 0; r < 8; r++) {
      l[r] += __shfl_xor(l[r], off);
#pragma unroll
      for (int d = 0; d < 8; d++) O[r][d] += __shfl_xor(O[r][d], off);
    }
  }
  if (seg == 0) {
#pragma unroll
    for (int r = 0; r < 8; r++) {
      float inv = 1.f / l[r];
      int n = C * 32 + rowg * 8 + r;
#pragma unroll
      for (int d = 0; d < 8; d++)
        abuf[((size_t)b * 64 + h * 8 + d) * NP + n] = O[r][d] * inv;
    }
  }
}

// ---------------------------------------------------------------------------
// Kernel 3: direct 3x3 conv, pad 1, stride 1, Cout=64, H=W=32.
// ---------------------------------------------------------------------------
template <int CINT>
__global__ __launch_bounds__(256) void conv3x3_kernel(
    const float* __restrict__ in,    // [8][CINT][32][32]
    const float* __restrict__ wgt,   // [64][CINT][3][3]
    const float* __restrict__ bias,  // [64]
    void* __restrict__ out,          // [8][128][32][32] bf16 or fp32
    int co_base, const int* __restrict__ flag)
{
  __shared__ float xt[16][10][34];
  __shared__ float wt[8][16][12];
  int rg = blockIdx.x, coG = blockIdx.y, b = blockIdx.z;
  int y0 = rg * 8;
  int t = threadIdx.x;
  int cog2 = t >> 7;
  int pg = t & 127;
  int row = pg >> 4, col = (pg & 15) * 2;

  float acc[4][2] = {{0.f, 0.f}, {0.f, 0.f}, {0.f, 0.f}, {0.f, 0.f}};

  for (int ci0 = 0; ci0 < CINT; ci0 += 16) {
    __syncthreads();
    {
      int pair = t >> 1, half = t & 1;
      for (int s = pair; s < 160; s += 128) {
        int ci = s / 10, rr = s - ci * 10;
        int gy = y0 - 1 + rr;
        const float* src = in + ((size_t)b * CINT + ci0 + ci) * 1024;
        int cc0 = half * 17;
        for (int cc = cc0; cc < cc0 + 17; cc++) {
          int gx = cc - 1;
          float v = 0.f;
          if ((unsigned)gy < 32u && (unsigned)gx < 32u) v = src[gy * 32 + gx];
          xt[ci][rr][cc] = v;
        }
      }
    }
    for (int s = t; s < 128; s += 256) {
      int co = s >> 4, ci = s & 15;
      const float* ws = wgt + ((size_t)(coG * 8 + co) * CINT + ci0 + ci) * 9;
#pragma unroll
      for (int k = 0; k < 9; k++) wt[co][ci][k] = ws[k];
    }
    __syncthreads();

    for (int ci = 0; ci < 16; ci++) {
      float xr[3][4];
#pragma unroll
      for (int ky = 0; ky < 3; ky++) {
        const float2* xp = (const float2*)&xt[ci][row + ky][col];
        float2 a = xp[0], c = xp[1];
        xr[ky][0] = a.x; xr[ky][1] = a.y; xr[ky][2] = c.x; xr[ky][3] = c.y;
      }
#pragma unroll
      for (int j = 0; j < 4; j++) {
        const float* wp = wt[cog2 * 4 + j][ci];
#pragma unroll
        for (int ky = 0; ky < 3; ky++)
#pragma unroll
          for (int kx = 0; kx < 3; kx++) {
            float wv = wp[ky * 3 + kx];
            acc[j][0] = fmaf(xr[ky][kx], wv, acc[j][0]);
            acc[j][1] = fmaf(xr[ky][kx + 1], wv, acc[j][1]);
          }
      }
    }
  }

  int f32 = *flag;
  int yy = y0 + row;
#pragma unroll
  for (int j = 0; j < 4; j++) {
    int co = coG * 8 + cog2 * 4 + j;
    float bv = bias[co];
    float v0 = acc[j][0] + bv, v1 = acc[j][1] + bv;
    size_t eoff = ((size_t)b * 128 + co_base + co) * 1024 + yy * 32 + col;
    if (f32) {
      float* op = (float*)out + eoff;
      op[0] = v0; op[1] = v1;
    } else {
      bf16* op = (bf16*)out + eoff;
      op[0] = __float2bfloat16(v0);
      op[1] = __float2bfloat16(v1);
    }
  }
}

// ---------------------------------------------------------------------------
extern "C" void kernel_launch(void* const* d_in, const int* in_sizes, int n_in,
                              void* d_out, int out_size, void* d_ws, size_t ws_size,
                              hipStream_t stream) {
  float* ws    = (float*)d_ws;
  float* xf    = ws;                 // 1048576
  float* wgf   = ws + 1048576;       // 73728
  float* wqkvf = ws + 1122304;       // 24576
  float* wof   = ws + 1146880;       // 36864
  float* bgf   = ws + 1183744;       // 64
  float* bqkvf = ws + 1183808;       // 192
  float* bof   = ws + 1184000;       // 64
  float* krhf  = ws + 1184064;       // 504
  float* krwf  = ws + 1184568;       // 504
  float* qbuf  = ws + 1185280;       // 524288
  float* kbuf  = qbuf + 524288;
  float* vbuf  = kbuf + 524288;
  float* abuf  = vbuf + 524288;
  int*   flag  = (int*)(ws + 3282432);

  detect_kernel<<<1, 256, 0, stream>>>((const unsigned*)d_in[0], flag);
  cvt_kernel<<<512, 256, 0, stream>>>(d_in[0], d_in[1], d_in[2], d_in[3], d_in[4],
                                      d_in[5], d_in[6], d_in[7], d_in[8], ws, flag);
  qkv_kernel<<<dim3(8, 16, 6), 256, 0, stream>>>(xf, wqkvf, bqkvf, qbuf, kbuf, vbuf);
  conv3x3_kernel<128><<<dim3(4, 8, 8), 256, 0, stream>>>(xf, wgf, bgf, d_out, 0, flag);
  attn_kernel<<<dim3(16, 8, 8), 256, 0, stream>>>(qbuf, kbuf, vbuf, krhf, krwf, abuf);
  conv3x3_kernel<64><<<dim3(4, 8, 8), 256, 0, stream>>>(abuf, wof, bof, d_out, 64, flag);
}

// Round 6
// 234.929 us; speedup vs baseline: 1.1449x; 1.0589x over previous
//
#include <hip/hip_runtime.h>
#include <hip/hip_bf16.h>

// AAConv2d: B=8, CIN=128, H=W=32, COUT=128, K=3, DK=DV=64, NH=8, dkh=dvh=8
// out[:, 0:64]  = conv3x3(x, w_general) + b_general
// out[:, 64:128]= conv3x3(attn_combined, w_out) + b_out
// Rel logits (verified): logits[n,m] += dot(q[:, m>>5, n>>5], krw[(m&31)-(m>>5)+31])
//                                    + dot(q[:, m>>5, n>>5], krh[(n&31)-(n>>5)+31])
// dtype detected at runtime (fp32 in practice); compute fp32.

#define NP 1024
#define QSCALE 2.8284271247461903f   // q / (8^-0.5) = q*sqrt(8)
#define LOG2E  1.4426950408889634f

using bf16 = __hip_bfloat16;

__device__ __forceinline__ float b2f(bf16 v) { return __bfloat162float(v); }

__device__ __forceinline__ float dot8(const float* a, const float* b) {
  float s = a[0] * b[0];
  s = fmaf(a[1], b[1], s); s = fmaf(a[2], b[2], s); s = fmaf(a[3], b[3], s);
  s = fmaf(a[4], b[4], s); s = fmaf(a[5], b[5], s); s = fmaf(a[6], b[6], s);
  s = fmaf(a[7], b[7], s);
  return s;
}

__device__ __forceinline__ int fenc(float f) { int i = __float_as_int(f); return i < 0 ? (i ^ 0x7fffffff) : i; }
__device__ __forceinline__ float fdec(int i) { return __int_as_float(i < 0 ? (i ^ 0x7fffffff) : i); }

#if defined(__has_builtin)
#if __has_builtin(__builtin_amdgcn_exp2f)
#define EXP2F __builtin_amdgcn_exp2f
#else
#define EXP2F exp2f
#endif
#else
#define EXP2F exp2f
#endif

// ---------------------------------------------------------------------------
// Kernel 0: dtype detector (bits 14:7 = low-bf16 exponent test).
// ---------------------------------------------------------------------------
__global__ __launch_bounds__(256) void detect_kernel(
    const unsigned* __restrict__ xraw, int* __restrict__ flag)
{
  __shared__ int partial[4];
  int t = threadIdx.x;
  int cnt = 0;
  for (int i = t; i < 1024; i += 256) {
    unsigned elo = (xraw[i] >> 7) & 0xffu;
    cnt += (elo >= 64u && elo <= 133u) ? 1 : 0;
  }
#pragma unroll
  for (int off = 1; off < 64; off <<= 1) cnt += __shfl_xor(cnt, off);
  if ((t & 63) == 0) partial[t >> 6] = cnt;
  __syncthreads();
  if (t == 0) {
    int tot = partial[0] + partial[1] + partial[2] + partial[3];
    *flag = (tot >= 650) ? 0 : 1;   // 1 = fp32 tensors, 0 = bf16 tensors
  }
}

// ---------------------------------------------------------------------------
// Kernel 0b: canonicalize all 9 inputs to fp32 in workspace.
// ---------------------------------------------------------------------------
__global__ __launch_bounds__(256) void cvt_kernel(
    const void* __restrict__ p0, const void* __restrict__ p1, const void* __restrict__ p2,
    const void* __restrict__ p3, const void* __restrict__ p4, const void* __restrict__ p5,
    const void* __restrict__ p6, const void* __restrict__ p7, const void* __restrict__ p8,
    float* __restrict__ ws, const int* __restrict__ flag)
{
  const void* src[9] = {p0, p1, p2, p3, p4, p5, p6, p7, p8};
  const int   n[9]    = {1048576, 73728, 64, 24576, 192, 36864, 64, 504, 504};
  const int   doff[9] = {0, 1048576, 1183744, 1122304, 1183808, 1146880, 1184000, 1184064, 1184568};
  int f32 = *flag;
  int gsz = gridDim.x * 256;
  int gid = blockIdx.x * 256 + threadIdx.x;
#pragma unroll
  for (int s = 0; s < 9; s++) {
    float* dst = ws + doff[s];
    int ns = n[s];
    if (f32) {
      const float* sp = (const float*)src[s];
      for (int i = gid; i < ns; i += gsz) dst[i] = sp[i];
    } else {
      const bf16* sp = (const bf16*)src[s];
      for (int i = gid; i < ns; i += gsz) dst[i] = b2f(sp[i]);
    }
  }
}

// ---------------------------------------------------------------------------
// Kernel 1: qkv 1x1 conv (fp32). grid (b=8, pg=16, cog=6), 256 threads.
// Outer-product micro-tile: thread = 4 co x 2 px; per ci: b64(x)+b128(w)+8 FMA.
// ---------------------------------------------------------------------------
__global__ __launch_bounds__(256) void qkv_kernel(
    const float* __restrict__ xf, const float* __restrict__ wf, const float* __restrict__ bias,
    float* __restrict__ qbuf, float* __restrict__ kbuf, float* __restrict__ vbuf)
{
  __shared__ float xt[128][64];   // ci x px, 32 KB
  __shared__ float wt[128][36];   // ci x co (32 used, pad 36: b128-aligned rows), 18 KB
  int b = blockIdx.x, pg = blockIdx.y, cog = blockIdx.z;
  int t = threadIdx.x;
  int p0 = pg * 64;
  const float* xs = xf + (size_t)b * 131072;
  for (int idx = t; idx < 8192; idx += 256) {
    int ci = idx >> 6, p = idx & 63;
    xt[ci][p] = xs[ci * 1024 + p0 + p];
  }
  for (int idx = t; idx < 4096; idx += 256) {
    int co = idx >> 7, ci = idx & 127;
    wt[ci][co] = wf[(cog * 32 + co) * 128 + ci];
  }
  __syncthreads();

  int cog2 = t >> 5;        // 0..7 -> 4 co each
  int pl = (t & 31) * 2;    // px pair
  float a0[4] = {0.f, 0.f, 0.f, 0.f};
  float a1[4] = {0.f, 0.f, 0.f, 0.f};
  for (int ci = 0; ci < 128; ci++) {
    float2 xv = *(const float2*)&xt[ci][pl];
    float4 wv = *(const float4*)&wt[ci][cog2 * 4];
    a0[0] = fmaf(xv.x, wv.x, a0[0]); a1[0] = fmaf(xv.y, wv.x, a1[0]);
    a0[1] = fmaf(xv.x, wv.y, a0[1]); a1[1] = fmaf(xv.y, wv.y, a1[1]);
    a0[2] = fmaf(xv.x, wv.z, a0[2]); a1[2] = fmaf(xv.y, wv.z, a1[2]);
    a0[3] = fmaf(xv.x, wv.w, a0[3]); a1[3] = fmaf(xv.y, wv.w, a1[3]);
  }
#pragma unroll
  for (int j = 0; j < 4; j++) {
    int co = cog * 32 + cog2 * 4 + j;
    float bv = bias[co];
    float v0 = a0[j] + bv, v1 = a1[j] + bv;
    float* dst;
    if (co < 64) { dst = qbuf; v0 *= QSCALE; v1 *= QSCALE; }
    else if (co < 128) dst = kbuf;
    else dst = vbuf;
    float2 pk; pk.x = v0; pk.y = v1;
    *(float2*)(dst + ((size_t)b * 64 + (co & 63)) * NP + p0 + pl) = pk;
  }
}

// ---------------------------------------------------------------------------
// Kernel 2: attention, single-pass upper-bound softmax, phase-split rows.
// grid (cp=16, h=8, b=8), 256 threads. Thread: 2 phases x 4 rows x 32 m-segs.
// Phase-split keeps live set (~100 VGPR) register-resident (round-5 post-
// mortem: 8-row version forced q rematerialization from global at VGPR=92).
// ---------------------------------------------------------------------------
__global__ __launch_bounds__(256, 2) void attn_kernel(
    const float* __restrict__ qbuf, const float* __restrict__ kbuf, const float* __restrict__ vbuf,
    const float* __restrict__ krh, const float* __restrict__ krw,
    float* __restrict__ abuf)
{
  __shared__ float Kt[NP][12];         // 48 KB, row m at [m][0..7]
  __shared__ float bw2[2][NP];         // 8 KB  (scaled by log2e)
  __shared__ float bhT[2][32][32];     // 8 KB  (scaled by log2e)
  __shared__ float qsT[2][32][8];      // 2 KB  (unscaled)
  __shared__ float krhs[64][8];        // 2 KB
  __shared__ float krws[64][8];        // 2 KB
  __shared__ int smax[3];              // bits(kmax^2), fenc(bwmax_s), fenc(bhmax_s)

  int t = threadIdx.x;
  int cp = blockIdx.x, h = blockIdx.y, b = blockIdx.z;
  int C0 = cp * 2;
  const float* qbase = qbuf + ((size_t)b * 64 + h * 8) * NP;
  const float* kbase = kbuf + ((size_t)b * 64 + h * 8) * NP;
  const float* vbase = vbuf + ((size_t)b * 64 + h * 8) * NP;

  if (t < 3) smax[t] = (t == 0) ? 0 : fenc(-3.0e38f);

  for (int idx = t; idx < 63 * 8; idx += 256) {
    krhs[idx >> 3][idx & 7] = krh[idx];
    krws[idx >> 3][idx & 7] = krw[idx];
  }
  for (int idx = t; idx < 512; idx += 256) {
    int cs = idx >> 8, d = (idx >> 5) & 7, r = idx & 31;
    qsT[cs][r][d] = qbase[(size_t)d * NP + r * 32 + (C0 + cs)];   // q[d][row=r][col=C]
  }
  // stage K rows, track max ||k||^2
  float kn2 = 0.f;
#pragma unroll
  for (int rr = 0; rr < 4; rr++) {
    int m = rr * 256 + t;
    const float4* ks = (const float4*)(kbase + (size_t)m * 8);
    float4 a = ks[0], c = ks[1];
    float4* kd = (float4*)&Kt[m][0];
    kd[0] = a; kd[1] = c;
    float nn = a.x * a.x + a.y * a.y + a.z * a.z + a.w * a.w +
               c.x * c.x + c.y * c.y + c.z * c.z + c.w * c.w;
    kn2 = fmaxf(kn2, nn);
  }
  __syncthreads();
  atomicMax(&smax[0], __float_as_int(kn2));   // kn2 >= 0: raw bits monotone

  float bwm = -3.0e38f;
  for (int idx = t; idx < 2048; idx += 256) {
    int cs = idx >> 10, m = idx & 1023;
    int rg = m >> 5, j2 = m & 31;
    float s = dot8(qsT[cs][rg], krws[j2 - rg + 31]) * LOG2E;
    bw2[cs][m] = s;
    bwm = fmaxf(bwm, s);
  }
  float bhm = -3.0e38f;
  for (int idx = t; idx < 2048; idx += 256) {
    int cs = idx >> 10, r = idx & 1023;
    int i = r >> 5, J = r & 31;
    float s = dot8(qsT[cs][i], krhs[J - (C0 + cs) + 31]) * LOG2E;
    bhT[cs][i][J] = s;
    bhm = fmaxf(bhm, s);
  }
  atomicMax(&smax[1], fenc(bwm));
  atomicMax(&smax[2], fenc(bhm));
  __syncthreads();

  float kmaxn = sqrtf(__int_as_float(smax[0]));
  float bmax = fdec(smax[1]) + fdec(smax[2]);

  int Csub = t >> 7, rowg = (t >> 5) & 3, seg = t & 31;
  int C = C0 + Csub;
  const float* bwX = bw2[Csub];
  const float* qrowbase = qbase + (size_t)C * 256 + rowg * 64;

#pragma unroll 1
  for (int ph = 0; ph < 2; ph++) {
    const float* qrow = qrowbase + ph * 32;
    float q[4][8], M[4], l[4], O[4][8];
#pragma unroll
    for (int r = 0; r < 4; r++) {
      float nn = 0.f;
#pragma unroll
      for (int d = 0; d < 8; d++) {
        float v = qrow[r * 8 + d] * LOG2E;
        q[r][d] = v;
        nn = fmaf(v, v, nn);
      }
      M[r] = sqrtf(nn) * kmaxn + bmax;   // safe scaled-domain upper bound
      l[r] = 0.f;
#pragma unroll
      for (int d = 0; d < 8; d++) O[r][d] = 0.f;
    }

    for (int i = 0; i < 32; ++i) {
      int m = i * 32 + seg;
      const float4* kp = (const float4*)&Kt[m][0];
      float4 ka = kp[0], kc = kp[1];
      float kk[8] = {ka.x, ka.y, ka.z, ka.w, kc.x, kc.y, kc.z, kc.w};
      const float4* vp = (const float4*)(vbase + (size_t)m * 8);
      float4 va = vp[0], vc = vp[1];
      float vv[8] = {va.x, va.y, va.z, va.w, vc.x, vc.y, vc.z, vc.w};
      float bwv = bwX[m];
      float4 bh4 = *(const float4*)&bhT[Csub][i][rowg * 8 + ph * 4];
      float cr[4] = {bh4.x, bh4.y, bh4.z, bh4.w};
#pragma unroll
      for (int r = 0; r < 4; ++r) {
        float s = bwv + (cr[r] - M[r]);
        s = fmaf(q[r][0], kk[0], s); s = fmaf(q[r][1], kk[1], s);
        s = fmaf(q[r][2], kk[2], s); s = fmaf(q[r][3], kk[3], s);
        s = fmaf(q[r][4], kk[4], s); s = fmaf(q[r][5], kk[5], s);
        s = fmaf(q[r][6], kk[6], s); s = fmaf(q[r][7], kk[7], s);
        float p = EXP2F(s);
        l[r] += p;
#pragma unroll
        for (int d = 0; d < 8; ++d) O[r][d] = fmaf(p, vv[d], O[r][d]);
      }
    }

    // reduce over the 32 segment lanes (xor < 32 stays in 32-lane halves)
#pragma unroll
    for (int off = 1; off < 32; off <<= 1) {
#pragma unroll
      for (int r = 0; r < 4; r++) {
        l[r] += __shfl_xor(l[r], off);
#pragma unroll
        for (int d = 0; d < 8; d++) O[r][d] += __shfl_xor(O[r][d], off);
      }
    }
    if (seg == 0) {
#pragma unroll
      for (int r = 0; r < 4; r++) {
        float inv = 1.f / l[r];
        int n = C * 32 + rowg * 8 + ph * 4 + r;
#pragma unroll
        for (int d = 0; d < 8; d++)
          abuf[((size_t)b * 64 + h * 8 + d) * NP + n] = O[r][d] * inv;
      }
    }
  }
}

// ---------------------------------------------------------------------------
// Kernel 3: direct 3x3 conv, pad 1, stride 1, Cout=64, H=W=32.
// grid (rg=8, coG=8, b=8) = 512 blocks (2/CU). Tile: 8 co x 4 rows x 32 cols.
// Thread: 2 co x 2 px. Weights read as float4 x2 + scalar (3 LDS/co/ci).
// ---------------------------------------------------------------------------
template <int CINT>
__global__ __launch_bounds__(256) void conv3x3_kernel(
    const float* __restrict__ in,    // [8][CINT][32][32]
    const float* __restrict__ wgt,   // [64][CINT][3][3]
    const float* __restrict__ bias,  // [64]
    void* __restrict__ out,          // [8][128][32][32] bf16 or fp32
    int co_base, const int* __restrict__ flag)
{
  __shared__ float xt[16][6][36];    // 13.8 KB: rows y0-1..y0+4, cols -1..32
  __shared__ float wt[8][16][12];    // 6 KB (9 used, b128-aligned rows)
  int rg = blockIdx.x, coG = blockIdx.y, b = blockIdx.z;
  int y0 = rg * 4;
  int t = threadIdx.x;
  int cog = t >> 6;                  // 0..3 -> 2 co each
  int pxg = t & 63;
  int row = pxg >> 4, col = (pxg & 15) * 2;

  float acc[2][2] = {{0.f, 0.f}, {0.f, 0.f}};

  for (int ci0 = 0; ci0 < CINT; ci0 += 16) {
    __syncthreads();
    if (t < 192) {
      int pair = t >> 1, half = t & 1;     // 96 (ci,rr) pairs x 2 col-halves
      int ci = pair / 6, rr = pair - ci * 6;
      int gy = y0 - 1 + rr;
      const float* src = in + ((size_t)b * CINT + ci0 + ci) * 1024 + gy * 32;
      bool rowok = (unsigned)gy < 32u;
      int cc0 = half * 17;
      for (int cc = cc0; cc < cc0 + 17; cc++) {
        int gx = cc - 1;
        float v = 0.f;
        if (rowok && (unsigned)gx < 32u) v = src[gx];
        xt[ci][rr][cc] = v;
      }
    }
    for (int s = t; s < 128; s += 256) {
      int co = s >> 4, ci = s & 15;
      const float* wsc = wgt + ((size_t)(coG * 8 + co) * CINT + ci0 + ci) * 9;
#pragma unroll
      for (int k = 0; k < 9; k++) wt[co][ci][k] = wsc[k];
    }
    __syncthreads();

    for (int ci = 0; ci < 16; ci++) {
      float xr[3][4];
#pragma unroll
      for (int ky = 0; ky < 3; ky++) {
        const float2* xp = (const float2*)&xt[ci][row + ky][col];
        float2 a = xp[0], c = xp[1];
        xr[ky][0] = a.x; xr[ky][1] = a.y; xr[ky][2] = c.x; xr[ky][3] = c.y;
      }
#pragma unroll
      for (int j = 0; j < 2; j++) {
        const float* wp = wt[cog * 2 + j][ci];
        float4 wA = *(const float4*)wp;
        float4 wB = *(const float4*)(wp + 4);
        float w8 = wp[8];
        float wv[9] = {wA.x, wA.y, wA.z, wA.w, wB.x, wB.y, wB.z, wB.w, w8};
#pragma unroll
        for (int ky = 0; ky < 3; ky++)
#pragma unroll
          for (int kx = 0; kx < 3; kx++) {
            float w = wv[ky * 3 + kx];
            acc[j][0] = fmaf(xr[ky][kx], w, acc[j][0]);
            acc[j][1] = fmaf(xr[ky][kx + 1], w, acc[j][1]);
          }
      }
    }
  }

  int f32 = *flag;
  int yy = y0 + row;
#pragma unroll
  for (int j = 0; j < 2; j++) {
    int co = coG * 8 + cog * 2 + j;
    float bv = bias[co];
    float v0 = acc[j][0] + bv, v1 = acc[j][1] + bv;
    size_t eoff = ((size_t)b * 128 + co_base + co) * 1024 + yy * 32 + col;
    if (f32) {
      float* op = (float*)out + eoff;
      op[0] = v0; op[1] = v1;
    } else {
      bf16* op = (bf16*)out + eoff;
      op[0] = __float2bfloat16(v0);
      op[1] = __float2bfloat16(v1);
    }
  }
}

// ---------------------------------------------------------------------------
extern "C" void kernel_launch(void* const* d_in, const int* in_sizes, int n_in,
                              void* d_out, int out_size, void* d_ws, size_t ws_size,
                              hipStream_t stream) {
  float* ws    = (float*)d_ws;
  float* xf    = ws;                 // 1048576
  float* wgf   = ws + 1048576;       // 73728
  float* wqkvf = ws + 1122304;       // 24576
  float* wof   = ws + 1146880;       // 36864
  float* bgf   = ws + 1183744;       // 64
  float* bqkvf = ws + 1183808;       // 192
  float* bof   = ws + 1184000;       // 64
  float* krhf  = ws + 1184064;       // 504
  float* krwf  = ws + 1184568;       // 504
  float* qbuf  = ws + 1185280;       // 524288
  float* kbuf  = qbuf + 524288;
  float* vbuf  = kbuf + 524288;
  float* abuf  = vbuf + 524288;
  int*   flag  = (int*)(ws + 3282432);

  detect_kernel<<<1, 256, 0, stream>>>((const unsigned*)d_in[0], flag);
  cvt_kernel<<<512, 256, 0, stream>>>(d_in[0], d_in[1], d_in[2], d_in[3], d_in[4],
                                      d_in[5], d_in[6], d_in[7], d_in[8], ws, flag);
  qkv_kernel<<<dim3(8, 16, 6), 256, 0, stream>>>(xf, wqkvf, bqkvf, qbuf, kbuf, vbuf);
  conv3x3_kernel<128><<<dim3(8, 8, 8), 256, 0, stream>>>(xf, wgf, bgf, d_out, 0, flag);
  attn_kernel<<<dim3(16, 8, 8), 256, 0, stream>>>(qbuf, kbuf, vbuf, krhf, krwf, abuf);
  conv3x3_kernel<64><<<dim3(8, 8, 8), 256, 0, stream>>>(abuf, wof, bof, d_out, 64, flag);
}